// Round 12
// baseline (2367.829 us; speedup 1.0000x reference)
//
#include <hip/hip_runtime.h>
#include <cstdint>
#include <cstddef>

#define TPB 256
#define PKS 16    // pk stride in u64 (atomic layout; perf-neutral per R9, kept)
#define NPW 25    // nodes per wave in tiled agg
#define TILEN 8192

// fp32 -> bf16 (round to nearest even), as raw ushort
__device__ __forceinline__ unsigned short f2bf(float f) {
  unsigned u = __float_as_uint(f);
  u += 0x7fffu + ((u >> 16) & 1u);
  return (unsigned short)(u >> 16);
}
__device__ __forceinline__ float bf_lo(unsigned u) { return __uint_as_float(u << 16); }
__device__ __forceinline__ float bf_hi(unsigned u) { return __uint_as_float(u & 0xffff0000u); }

#define FIXP 262144.0f   // 2^18 fixed-point scale for weighted degree
#define LOWMASK 0xFFFFFFFFFFULL

typedef __attribute__((ext_vector_type(8))) short  short8v;   // 8 bf16 (4 VGPRs)
typedef __attribute__((ext_vector_type(4))) float  float4v;   // MFMA acc

// ---------------- preprocessing ----------------

__global__ void init_k(unsigned long long* __restrict__ pk, int n) {
  int i = blockIdx.x * TPB + threadIdx.x;
  if (i < n * PKS) pk[i] = 0ULL;
}

// ONE packed atomic per edge: count in high 24 bits, fixed-point weighted degree in
// low 40 bits. Returned old count field = this edge's slot within its CSR row.
__global__ void edges_k(const int* __restrict__ ei, const float* __restrict__ w,
                        unsigned long long* __restrict__ pk, int* __restrict__ pir, int E) {
  int e = blockIdx.x * TPB + threadIdx.x;
  if (e >= E) return;
  int d = ei[E + e];
  unsigned long long v = (1ULL << 40) | (unsigned long long)(w[e] * FIXP + 0.5f);
  unsigned long long old = atomicAdd(&pk[(size_t)d * PKS], v);
  pir[e] = (int)(old >> 40);
}

__global__ void unpack_k(const unsigned long long* __restrict__ pk,
                         float* __restrict__ dinv, int* __restrict__ cnt, int n) {
  int i = blockIdx.x * TPB + threadIdx.x;
  if (i >= n) return;
  unsigned long long p = pk[(size_t)i * PKS];
  float deg = 1.0f + (float)(p & LOWMASK) * (1.0f / FIXP);   // self-loop weight 1 => deg >= 1
  dinv[i] = rsqrtf(deg);
  cnt[i]  = (int)(p >> 40);
}

__global__ void scan_a(const int* __restrict__ cnt, int* __restrict__ rp,
                       int* __restrict__ bsum, int n) {
  __shared__ int s[TPB];
  int i = blockIdx.x * TPB + threadIdx.x;
  int v = (i < n) ? cnt[i] : 0;
  s[threadIdx.x] = v;
  __syncthreads();
  #pragma unroll
  for (int off = 1; off < TPB; off <<= 1) {
    int t = (threadIdx.x >= off) ? s[threadIdx.x - off] : 0;
    __syncthreads();
    s[threadIdx.x] += t;
    __syncthreads();
  }
  if (i < n) rp[i] = s[threadIdx.x] - v;            // exclusive within block
  if (threadIdx.x == TPB - 1) bsum[blockIdx.x] = s[TPB - 1];
}

__global__ void scan_b(int* __restrict__ bsum, int nb) {
  __shared__ int s[512];
  int v = (threadIdx.x < nb) ? bsum[threadIdx.x] : 0;
  s[threadIdx.x] = v;
  __syncthreads();
  #pragma unroll
  for (int off = 1; off < 512; off <<= 1) {
    int t = (threadIdx.x >= off) ? s[threadIdx.x - off] : 0;
    __syncthreads();
    s[threadIdx.x] += t;
    __syncthreads();
  }
  if (threadIdx.x < nb) bsum[threadIdx.x] = s[threadIdx.x] - v;  // exclusive block offsets
}

__global__ void scan_c(int* __restrict__ rp, const int* __restrict__ bsum, int n, int etot) {
  int i = blockIdx.x * TPB + threadIdx.x;
  if (i < n) rp[i] += bsum[blockIdx.x];
  if (blockIdx.x == 0 && threadIdx.x == 0) rp[n] = etot;
}

// no atomic: slot comes from pir[] captured by the packed atomic
__global__ void fill_k(const int* __restrict__ ei, const float* __restrict__ w,
                       const float* __restrict__ dinv, const int* __restrict__ rp,
                       const int* __restrict__ pir, int2* __restrict__ epk, int E) {
  int e = blockIdx.x * TPB + threadIdx.x;
  if (e >= E) return;
  int s = ei[e];
  int d = ei[E + e];
  int pos = rp[d] + pir[e];
  float nrm = dinv[s] * w[e] * dinv[d];
  epk[pos] = make_int2(s, __float_as_int(nrm));
}

// sort each CSR row by src (ascending) — gather locality for the tiled agg.
// Correctness of the tiled agg does NOT depend on sortedness (prefix-consumption
// is order-safe); this only tightens the per-tile access window.
__global__ __launch_bounds__(256) void sort_rows(int2* __restrict__ epk,
                                                 const int* __restrict__ rp, int n) {
  int wid  = blockIdx.x * 4 + (threadIdx.x >> 6);
  int lane = threadIdx.x & 63;
  if (wid >= n) return;
  int e0 = rp[wid], e1 = rp[wid + 1];
  int deg = e1 - e0;
  if (deg <= 1 || deg > 64) return;
  unsigned long long val = ~0ULL;
  if (lane < deg) {
    int2 p = epk[e0 + lane];
    val = ((unsigned long long)(unsigned)p.x << 32) | (unsigned)p.y;
  }
  #pragma unroll
  for (int k = 2; k <= 64; k <<= 1) {
    #pragma unroll
    for (int j = k >> 1; j >= 1; j >>= 1) {
      unsigned long long o = __shfl_xor(val, j, 64);
      bool takeMin = (((lane & j) == 0) == ((lane & k) == 0));
      unsigned long long mn = val < o ? val : o;
      unsigned long long mx = val < o ? o : val;
      val = takeMin ? mn : mx;
    }
  }
  if (lane < deg)
    epk[e0 + lane] = make_int2((int)(val >> 32), (int)(unsigned)(val & 0xffffffffu));
}

// transpose + bf16-convert all three weight matrices: wtX[c][k] = W[k][c]
__global__ void wt_k(const float* __restrict__ W1, const float* __restrict__ W2,
                     const float* __restrict__ W3,
                     unsigned short* __restrict__ wt1, unsigned short* __restrict__ wt2,
                     unsigned short* __restrict__ wt3) {
  int t = blockIdx.x * TPB + threadIdx.x;
  if (t < 16384) {                  // W1 128x128
    int c = t >> 7, k = t & 127;
    wt1[t] = f2bf(W1[k * 128 + c]);
  } else if (t < 32768) {           // W2 128x128
    int u = t - 16384;
    int c = u >> 7, k = u & 127;
    wt2[u] = f2bf(W2[k * 128 + c]);
  } else if (t < 40960) {           // W3 128x64
    int u = t - 32768;
    int c = u >> 7, k = u & 127;
    wt3[u] = f2bf(W3[k * 64 + c]);
  }
}

// ---------------- GEMM via MFMA: H = bf16(act(X)) @ bf16(W), fp32 acc, bf16 out ----

template<int COUT, bool RELU>
__global__ __launch_bounds__(256) void gemm_mfma(const float* __restrict__ X,
                                                 const unsigned short* __restrict__ Wt,
                                                 unsigned short* __restrict__ H, int n) {
  const int lane = threadIdx.x & 63;
  const int wv   = threadIdx.x >> 6;             // 0..3
  const int r0   = (blockIdx.x * 4 + wv) * 16;   // wave's row strip
  if (r0 >= n) return;
  const int c16   = lane & 15;
  const int kb    = (lane >> 4) * 8;             // 0,8,16,24
  const int row_c = min(r0 + c16, n - 1);        // clamp OOB loads

  short8v a[4];
  const float* xrow = X + (size_t)row_c * 128;
  #pragma unroll
  for (int kk = 0; kk < 4; kk++) {
    float4 lo = *(const float4*)(xrow + kk * 32 + kb);
    float4 hi = *(const float4*)(xrow + kk * 32 + kb + 4);
    float v0 = lo.x, v1 = lo.y, v2 = lo.z, v3 = lo.w;
    float v4 = hi.x, v5 = hi.y, v6 = hi.z, v7 = hi.w;
    if (RELU) {
      v0 = fmaxf(v0, 0.f); v1 = fmaxf(v1, 0.f); v2 = fmaxf(v2, 0.f); v3 = fmaxf(v3, 0.f);
      v4 = fmaxf(v4, 0.f); v5 = fmaxf(v5, 0.f); v6 = fmaxf(v6, 0.f); v7 = fmaxf(v7, 0.f);
    }
    short8v t;
    t[0] = (short)f2bf(v0); t[1] = (short)f2bf(v1);
    t[2] = (short)f2bf(v2); t[3] = (short)f2bf(v3);
    t[4] = (short)f2bf(v4); t[5] = (short)f2bf(v5);
    t[6] = (short)f2bf(v6); t[7] = (short)f2bf(v7);
    a[kk] = t;
  }

  constexpr int CT = COUT / 16;
  const int orow = r0 + (lane >> 4) * 4;
  #pragma unroll
  for (int ct = 0; ct < CT; ct++) {
    float4v acc = {0.f, 0.f, 0.f, 0.f};
    const unsigned short* wrow = Wt + (size_t)(ct * 16 + c16) * 128 + kb;
    #pragma unroll
    for (int kk = 0; kk < 4; kk++) {
      short8v b = *(const short8v*)(wrow + kk * 32);
      acc = __builtin_amdgcn_mfma_f32_16x16x32_bf16(a[kk], b, acc, 0, 0, 0);
    }
    const int ocol = ct * 16 + c16;
    #pragma unroll
    for (int r = 0; r < 4; r++) {
      if (orow + r < n)
        H[(size_t)(orow + r) * COUT + ocol] = f2bf(acc[r]);
    }
  }
}

// ---------------- tiled persistent aggregation ----------------
// Persistent: grid = ceil(n/(NPW*4)) blocks, each wave owns NPW consecutive nodes,
// accumulators live in VGPRs across a loop over src-tiles (TILEN nodes = 2MB bf16 @128ch).
// All co-resident waves gather within the same tile window -> L2-resident gathers.
// Rows are consumed as maximal prefixes with src < tile_hi (order-safe; sortedness
// only improves locality). Dual-edge step gives 2 outstanding gathers per wave.

template<int CH>
__global__ __launch_bounds__(256, 4) void agg_tiled(const unsigned short* __restrict__ H,
                                                    const int* __restrict__ rp,
                                                    const int2* __restrict__ epk,
                                                    const float* __restrict__ dinv,
                                                    const float* __restrict__ bias,
                                                    float* __restrict__ OUT,
                                                    int n, int nt) {
  const int lane = threadIdx.x & 63;
  const int gw   = blockIdx.x * 4 + (threadIdx.x >> 6);
  const int base = gw * NPW;

  float ax[NPW], ay[NPW];
  int   ptr[NPW];
  #pragma unroll
  for (int i = 0; i < NPW; i++) { ax[i] = 0.f; ay[i] = 0.f; ptr[i] = 0; }
  #pragma unroll
  for (int i = 0; i < NPW; i++) {
    int node = base + i;
    if (node < n) ptr[i] = rp[node];
  }
  float bx = 0.f, by = 0.f;
  if (CH == 128) { float2 bv = ((const float2*)bias)[lane]; bx = bv.x; by = bv.y; }
  else           { bx = bias[lane]; }

  for (int t = 0; t < nt; t++) {
    const int lo = t * TILEN, hi = lo + TILEN;
    #pragma unroll
    for (int i = 0; i < NPW; i++) {
      int node = base + i;
      if (node >= n) continue;
      // self term + bias, once (node lies in exactly one tile)
      if (node >= lo && node < hi) {
        float di = dinv[node];
        float w0 = di * di;
        if (CH == 128) {
          unsigned hv = ((const unsigned*)(H + (size_t)node * 128))[lane];
          ax[i] += bx + w0 * bf_lo(hv);
          ay[i] += by + w0 * bf_hi(hv);
        } else {
          float hv = __uint_as_float(((unsigned)H[(size_t)node * 64 + lane]) << 16);
          ax[i] += bx + w0 * hv;
        }
      }
      const int rend = rp[node + 1];
      int e = ptr[i];
      for (;;) {
        if (e >= rend) break;
        int2 p0 = epk[e];
        if (p0.x >= hi) break;
        int2 p1 = p0;
        bool two = false;
        if (e + 1 < rend) { p1 = epk[e + 1]; two = (p1.x < hi); }
        if (CH == 128) {
          unsigned h0 = ((const unsigned*)(H + (size_t)p0.x * 128))[lane];
          unsigned h1 = two ? ((const unsigned*)(H + (size_t)p1.x * 128))[lane] : 0u;
          float n0 = __int_as_float(p0.y);
          ax[i] += n0 * bf_lo(h0); ay[i] += n0 * bf_hi(h0);
          if (two) {
            float n1 = __int_as_float(p1.y);
            ax[i] += n1 * bf_lo(h1); ay[i] += n1 * bf_hi(h1);
          }
        } else {
          float h0 = __uint_as_float(((unsigned)H[(size_t)p0.x * 64 + lane]) << 16);
          float h1 = two ? __uint_as_float(((unsigned)H[(size_t)p1.x * 64 + lane]) << 16) : 0.f;
          ax[i] += __int_as_float(p0.y) * h0;
          if (two) ax[i] += __int_as_float(p1.y) * h1;
        }
        e += two ? 2 : 1;
      }
      ptr[i] = e;
    }
  }

  #pragma unroll
  for (int i = 0; i < NPW; i++) {
    int node = base + i;
    if (node < n) {
      if (CH == 128) {
        ((float2*)(OUT + (size_t)node * 128))[lane] = make_float2(ax[i], ay[i]);
      } else {
        OUT[(size_t)node * 64 + lane] = ax[i];
      }
    }
  }
}

// ---------------- launch ----------------

extern "C" void kernel_launch(void* const* d_in, const int* in_sizes, int n_in,
                              void* d_out, int out_size, void* d_ws, size_t ws_size,
                              hipStream_t stream) {
  const float* x  = (const float*)d_in[0];
  const int*   ei = (const int*)d_in[1];    // int64 in reference -> int32 on device
  const float* ew = (const float*)d_in[2];
  const float* W1 = (const float*)d_in[3];
  const float* b1 = (const float*)d_in[4];
  const float* W2 = (const float*)d_in[5];
  const float* b2 = (const float*)d_in[6];
  const float* W3 = (const float*)d_in[7];
  const float* b3 = (const float*)d_in[8];

  const int N = in_sizes[0] / 128;
  const int E = in_sizes[2];

  char* p = (char*)d_ws;
  auto carve = [&](size_t bytes) -> void* {
    void* r = (void*)p;
    p += (bytes + 255) & ~(size_t)255;
    return r;
  };
  unsigned long long* pk = (unsigned long long*)carve((size_t)N * 8 * PKS);
  float* dinv   = (float*)carve((size_t)N * 4);
  int*   cnt    = (int*)  carve((size_t)N * 4);
  int*   rp     = (int*)  carve((size_t)(N + 1) * 4);
  int*   bsum   = (int*)  carve(512 * 4);
  int*   pir    = (int*)  carve((size_t)E * 4);
  int2*  epk    = (int2*) carve((size_t)E * 8);
  unsigned short* hbuf = (unsigned short*)carve((size_t)N * 128 * 2);  // bf16 table
  float* abuf   = (float*)carve((size_t)N * 128 * 4);
  unsigned short* wt1 = (unsigned short*)carve(16384 * 2);
  unsigned short* wt2 = (unsigned short*)carve(16384 * 2);
  unsigned short* wt3 = (unsigned short*)carve(8192 * 2);

  const int NB = (N + TPB - 1) / TPB;
  const int EB = (E + TPB - 1) / TPB;

  // graph preprocessing + weight transpose (once per call; reused by all 3 layers)
  init_k<<<(N * PKS + TPB - 1) / TPB, TPB, 0, stream>>>(pk, N);
  edges_k<<<EB, TPB, 0, stream>>>(ei, ew, pk, pir, E);
  unpack_k<<<NB, TPB, 0, stream>>>(pk, dinv, cnt, N);
  scan_a<<<NB, TPB, 0, stream>>>(cnt, rp, bsum, N);
  scan_b<<<1, 512, 0, stream>>>(bsum, NB);
  scan_c<<<NB, TPB, 0, stream>>>(rp, bsum, N, E);
  fill_k<<<EB, TPB, 0, stream>>>(ei, ew, dinv, rp, pir, epk, E);
  wt_k<<<160, TPB, 0, stream>>>(W1, W2, W3, wt1, wt2, wt3);
  sort_rows<<<(N + 3) / 4, 256, 0, stream>>>(epk, rp, N);

  const int gemmBlocks = (N + 63) / 64;              // 4 waves x 16 rows per block
  const int aggBlocks  = (N + NPW * 4 - 1) / (NPW * 4);  // persistent tiled agg
  const int nt         = (N + TILEN - 1) / TILEN;

  // layer 1: h = x @ W1 (bf16 mfma) ; agg + b1 -> abuf fp32
  gemm_mfma<128, false><<<gemmBlocks, 256, 0, stream>>>(x, wt1, hbuf, N);
  agg_tiled<128><<<aggBlocks, 256, 0, stream>>>(hbuf, rp, epk, dinv, b1, abuf, N, nt);

  // layer 2: h = relu(a1) @ W2 ; agg + b2 -> abuf fp32
  gemm_mfma<128, true><<<gemmBlocks, 256, 0, stream>>>(abuf, wt2, hbuf, N);
  agg_tiled<128><<<aggBlocks, 256, 0, stream>>>(hbuf, rp, epk, dinv, b2, abuf, N, nt);

  // layer 3: h = relu(a2) @ W3 ; agg + b3 -> d_out fp32
  gemm_mfma<64, true><<<gemmBlocks, 256, 0, stream>>>(abuf, wt3, hbuf, N);
  agg_tiled<64><<<aggBlocks, 256, 0, stream>>>(hbuf, rp, epk, dinv, b3, (float*)d_out, N, nt);
}

// Round 13
// 385.061 us; speedup vs baseline: 6.1492x; 6.1492x over previous
//
#include <hip/hip_runtime.h>
#include <cstdint>
#include <cstddef>

#define TPB 256
#define PKS 16   // pk stride in u64 (atomic layout; perf-neutral per R9, kept)

// fp32 -> bf16 (round to nearest even), as raw ushort
__device__ __forceinline__ unsigned short f2bf(float f) {
  unsigned u = __float_as_uint(f);
  u += 0x7fffu + ((u >> 16) & 1u);
  return (unsigned short)(u >> 16);
}
__device__ __forceinline__ float bf_lo(unsigned u) { return __uint_as_float(u << 16); }
__device__ __forceinline__ float bf_hi(unsigned u) { return __uint_as_float(u & 0xffff0000u); }

#define FIXP 262144.0f   // 2^18 fixed-point scale for weighted degree
#define LOWMASK 0xFFFFFFFFFFULL

typedef __attribute__((ext_vector_type(8))) short  short8v;   // 8 bf16 (4 VGPRs)
typedef __attribute__((ext_vector_type(4))) float  float4v;   // MFMA acc

// ---------------- preprocessing ----------------

__global__ void init_k(unsigned long long* __restrict__ pk, int n) {
  int i = blockIdx.x * TPB + threadIdx.x;
  if (i < n * PKS) pk[i] = 0ULL;
}

// ONE packed atomic per edge: count in high 24 bits, fixed-point weighted degree in
// low 40 bits. Returned old count field = this edge's slot within its CSR row.
__global__ void edges_k(const int* __restrict__ ei, const float* __restrict__ w,
                        unsigned long long* __restrict__ pk, int* __restrict__ pir, int E) {
  int e = blockIdx.x * TPB + threadIdx.x;
  if (e >= E) return;
  int d = ei[E + e];
  unsigned long long v = (1ULL << 40) | (unsigned long long)(w[e] * FIXP + 0.5f);
  unsigned long long old = atomicAdd(&pk[(size_t)d * PKS], v);
  pir[e] = (int)(old >> 40);
}

__global__ void unpack_k(const unsigned long long* __restrict__ pk,
                         float* __restrict__ dinv, int* __restrict__ cnt, int n) {
  int i = blockIdx.x * TPB + threadIdx.x;
  if (i >= n) return;
  unsigned long long p = pk[(size_t)i * PKS];
  float deg = 1.0f + (float)(p & LOWMASK) * (1.0f / FIXP);   // self-loop weight 1 => deg >= 1
  dinv[i] = rsqrtf(deg);
  cnt[i]  = (int)(p >> 40);
}

__global__ void scan_a(const int* __restrict__ cnt, int* __restrict__ rp,
                       int* __restrict__ bsum, int n) {
  __shared__ int s[TPB];
  int i = blockIdx.x * TPB + threadIdx.x;
  int v = (i < n) ? cnt[i] : 0;
  s[threadIdx.x] = v;
  __syncthreads();
  #pragma unroll
  for (int off = 1; off < TPB; off <<= 1) {
    int t = (threadIdx.x >= off) ? s[threadIdx.x - off] : 0;
    __syncthreads();
    s[threadIdx.x] += t;
    __syncthreads();
  }
  if (i < n) rp[i] = s[threadIdx.x] - v;            // exclusive within block
  if (threadIdx.x == TPB - 1) bsum[blockIdx.x] = s[TPB - 1];
}

__global__ void scan_b(int* __restrict__ bsum, int nb) {
  __shared__ int s[512];
  int v = (threadIdx.x < nb) ? bsum[threadIdx.x] : 0;
  s[threadIdx.x] = v;
  __syncthreads();
  #pragma unroll
  for (int off = 1; off < 512; off <<= 1) {
    int t = (threadIdx.x >= off) ? s[threadIdx.x - off] : 0;
    __syncthreads();
    s[threadIdx.x] += t;
    __syncthreads();
  }
  if (threadIdx.x < nb) bsum[threadIdx.x] = s[threadIdx.x] - v;  // exclusive block offsets
}

__global__ void scan_c(int* __restrict__ rp, const int* __restrict__ bsum, int n, int etot) {
  int i = blockIdx.x * TPB + threadIdx.x;
  if (i < n) rp[i] += bsum[blockIdx.x];
  if (blockIdx.x == 0 && threadIdx.x == 0) rp[n] = etot;
}

// no atomic: slot comes from pir[] captured by the packed atomic
__global__ void fill_k(const int* __restrict__ ei, const float* __restrict__ w,
                       const float* __restrict__ dinv, const int* __restrict__ rp,
                       const int* __restrict__ pir, int2* __restrict__ epk, int E) {
  int e = blockIdx.x * TPB + threadIdx.x;
  if (e >= E) return;
  int s = ei[e];
  int d = ei[E + e];
  int pos = rp[d] + pir[e];
  float nrm = dinv[s] * w[e] * dinv[d];
  epk[pos] = make_int2(s, __float_as_int(nrm));
}

// transpose + bf16-convert all three weight matrices: wtX[c][k] = W[k][c]
__global__ void wt_k(const float* __restrict__ W1, const float* __restrict__ W2,
                     const float* __restrict__ W3,
                     unsigned short* __restrict__ wt1, unsigned short* __restrict__ wt2,
                     unsigned short* __restrict__ wt3) {
  int t = blockIdx.x * TPB + threadIdx.x;
  if (t < 16384) {                  // W1 128x128
    int c = t >> 7, k = t & 127;
    wt1[t] = f2bf(W1[k * 128 + c]);
  } else if (t < 32768) {           // W2 128x128
    int u = t - 16384;
    int c = u >> 7, k = u & 127;
    wt2[u] = f2bf(W2[k * 128 + c]);
  } else if (t < 40960) {           // W3 128x64
    int u = t - 32768;
    int c = u >> 7, k = u & 127;
    wt3[u] = f2bf(W3[k * 64 + c]);
  }
}

// ---------------- GEMM via MFMA: H = bf16(act(X)) @ bf16(W), fp32 acc, bf16 out ----

template<int COUT, bool RELU>
__global__ __launch_bounds__(256) void gemm_mfma(const float* __restrict__ X,
                                                 const unsigned short* __restrict__ Wt,
                                                 unsigned short* __restrict__ H, int n) {
  const int lane = threadIdx.x & 63;
  const int wv   = threadIdx.x >> 6;             // 0..3
  const int r0   = (blockIdx.x * 4 + wv) * 16;   // wave's row strip
  if (r0 >= n) return;
  const int c16   = lane & 15;
  const int kb    = (lane >> 4) * 8;             // 0,8,16,24
  const int row_c = min(r0 + c16, n - 1);        // clamp OOB loads

  short8v a[4];
  const float* xrow = X + (size_t)row_c * 128;
  #pragma unroll
  for (int kk = 0; kk < 4; kk++) {
    float4 lo = *(const float4*)(xrow + kk * 32 + kb);
    float4 hi = *(const float4*)(xrow + kk * 32 + kb + 4);
    float v0 = lo.x, v1 = lo.y, v2 = lo.z, v3 = lo.w;
    float v4 = hi.x, v5 = hi.y, v6 = hi.z, v7 = hi.w;
    if (RELU) {
      v0 = fmaxf(v0, 0.f); v1 = fmaxf(v1, 0.f); v2 = fmaxf(v2, 0.f); v3 = fmaxf(v3, 0.f);
      v4 = fmaxf(v4, 0.f); v5 = fmaxf(v5, 0.f); v6 = fmaxf(v6, 0.f); v7 = fmaxf(v7, 0.f);
    }
    short8v t;
    t[0] = (short)f2bf(v0); t[1] = (short)f2bf(v1);
    t[2] = (short)f2bf(v2); t[3] = (short)f2bf(v3);
    t[4] = (short)f2bf(v4); t[5] = (short)f2bf(v5);
    t[6] = (short)f2bf(v6); t[7] = (short)f2bf(v7);
    a[kk] = t;
  }

  constexpr int CT = COUT / 16;
  const int orow = r0 + (lane >> 4) * 4;
  #pragma unroll
  for (int ct = 0; ct < CT; ct++) {
    float4v acc = {0.f, 0.f, 0.f, 0.f};
    const unsigned short* wrow = Wt + (size_t)(ct * 16 + c16) * 128 + kb;
    #pragma unroll
    for (int kk = 0; kk < 4; kk++) {
      short8v b = *(const short8v*)(wrow + kk * 32);
      acc = __builtin_amdgcn_mfma_f32_16x16x32_bf16(a[kk], b, acc, 0, 0, 0);
    }
    const int ocol = ct * 16 + c16;
    #pragma unroll
    for (int r = 0; r < 4; r++) {
      if (orow + r < n)
        H[(size_t)(orow + r) * COUT + ocol] = f2bf(acc[r]);
    }
  }
}

// ---------------- aggregation: one wave per node, CSR gather (bf16 table) ----------
// out[j][c] = b[c] + dinv[j]^2 * h[j][c] + sum_e norm_e * h[col_e][c]
// 16-deep gather unroll: 16 outstanding 256B row-gathers per wave (MLP).

__global__ __launch_bounds__(256) void agg128(const unsigned short* __restrict__ H,
                                              const int* __restrict__ rp,
                                              const int2* __restrict__ epk,
                                              const float* __restrict__ dinv,
                                              const float* __restrict__ bias,
                                              float* __restrict__ OUT, int n) {
  int wid  = __builtin_amdgcn_readfirstlane(blockIdx.x * 4 + (threadIdx.x >> 6));
  int lane = threadIdx.x & 63;
  if (wid >= n) return;
  float di = dinv[wid];
  float w0 = di * di;
  unsigned hv = ((const unsigned*)(H + (size_t)wid * 128))[lane];
  float2 bv = ((const float2*)bias)[lane];
  float ax = bv.x + w0 * bf_lo(hv);
  float ay = bv.y + w0 * bf_hi(hv);
  int e  = rp[wid];
  int e1 = rp[wid + 1];
  for (; e + 15 < e1; e += 16) {
    int2 p[16];
    #pragma unroll
    for (int u = 0; u < 16; u++) p[u] = epk[e + u];
    unsigned h[16];
    #pragma unroll
    for (int u = 0; u < 16; u++) h[u] = ((const unsigned*)(H + (size_t)p[u].x * 128))[lane];
    #pragma unroll
    for (int u = 0; u < 16; u++) {
      float nw = __int_as_float(p[u].y);
      ax += nw * bf_lo(h[u]);
      ay += nw * bf_hi(h[u]);
    }
  }
  for (; e + 3 < e1; e += 4) {
    int2 p[4];
    #pragma unroll
    for (int u = 0; u < 4; u++) p[u] = epk[e + u];
    unsigned h[4];
    #pragma unroll
    for (int u = 0; u < 4; u++) h[u] = ((const unsigned*)(H + (size_t)p[u].x * 128))[lane];
    #pragma unroll
    for (int u = 0; u < 4; u++) {
      float nw = __int_as_float(p[u].y);
      ax += nw * bf_lo(h[u]);
      ay += nw * bf_hi(h[u]);
    }
  }
  for (; e < e1; e++) {
    int2 p = epk[e];
    unsigned h = ((const unsigned*)(H + (size_t)p.x * 128))[lane];
    float nw = __int_as_float(p.y);
    ax += nw * bf_lo(h); ay += nw * bf_hi(h);
  }
  ((float2*)(OUT + (size_t)wid * 128))[lane] = make_float2(ax, ay);
}

__global__ __launch_bounds__(256) void agg64(const unsigned short* __restrict__ H,
                                             const int* __restrict__ rp,
                                             const int2* __restrict__ epk,
                                             const float* __restrict__ dinv,
                                             const float* __restrict__ bias,
                                             float* __restrict__ OUT, int n) {
  int wid  = __builtin_amdgcn_readfirstlane(blockIdx.x * 4 + (threadIdx.x >> 6));
  int lane = threadIdx.x & 63;
  if (wid >= n) return;
  float di = dinv[wid];
  float w0 = di * di;
  float hv = __uint_as_float(((unsigned)H[(size_t)wid * 64 + lane]) << 16);
  float acc = bias[lane] + w0 * hv;
  int e  = rp[wid];
  int e1 = rp[wid + 1];
  for (; e + 15 < e1; e += 16) {
    int2 p[16];
    #pragma unroll
    for (int u = 0; u < 16; u++) p[u] = epk[e + u];
    float h[16];
    #pragma unroll
    for (int u = 0; u < 16; u++)
      h[u] = __uint_as_float(((unsigned)H[(size_t)p[u].x * 64 + lane]) << 16);
    #pragma unroll
    for (int u = 0; u < 16; u++) acc += __int_as_float(p[u].y) * h[u];
  }
  for (; e + 3 < e1; e += 4) {
    int2 p[4];
    #pragma unroll
    for (int u = 0; u < 4; u++) p[u] = epk[e + u];
    float h[4];
    #pragma unroll
    for (int u = 0; u < 4; u++)
      h[u] = __uint_as_float(((unsigned)H[(size_t)p[u].x * 64 + lane]) << 16);
    #pragma unroll
    for (int u = 0; u < 4; u++) acc += __int_as_float(p[u].y) * h[u];
  }
  for (; e < e1; e++) {
    int2 p = epk[e];
    float h = __uint_as_float(((unsigned)H[(size_t)p.x * 64 + lane]) << 16);
    acc += __int_as_float(p.y) * h;
  }
  OUT[(size_t)wid * 64 + lane] = acc;
}

// ---------------- launch ----------------

extern "C" void kernel_launch(void* const* d_in, const int* in_sizes, int n_in,
                              void* d_out, int out_size, void* d_ws, size_t ws_size,
                              hipStream_t stream) {
  const float* x  = (const float*)d_in[0];
  const int*   ei = (const int*)d_in[1];    // int64 in reference -> int32 on device
  const float* ew = (const float*)d_in[2];
  const float* W1 = (const float*)d_in[3];
  const float* b1 = (const float*)d_in[4];
  const float* W2 = (const float*)d_in[5];
  const float* b2 = (const float*)d_in[6];
  const float* W3 = (const float*)d_in[7];
  const float* b3 = (const float*)d_in[8];

  const int N = in_sizes[0] / 128;
  const int E = in_sizes[2];

  char* p = (char*)d_ws;
  auto carve = [&](size_t bytes) -> void* {
    void* r = (void*)p;
    p += (bytes + 255) & ~(size_t)255;
    return r;
  };
  unsigned long long* pk = (unsigned long long*)carve((size_t)N * 8 * PKS);
  float* dinv   = (float*)carve((size_t)N * 4);
  int*   cnt    = (int*)  carve((size_t)N * 4);
  int*   rp     = (int*)  carve((size_t)(N + 1) * 4);
  int*   bsum   = (int*)  carve(512 * 4);
  int*   pir    = (int*)  carve((size_t)E * 4);
  int2*  epk    = (int2*) carve((size_t)E * 8);
  unsigned short* hbuf = (unsigned short*)carve((size_t)N * 128 * 2);  // bf16 table
  float* abuf   = (float*)carve((size_t)N * 128 * 4);
  unsigned short* wt1 = (unsigned short*)carve(16384 * 2);
  unsigned short* wt2 = (unsigned short*)carve(16384 * 2);
  unsigned short* wt3 = (unsigned short*)carve(8192 * 2);

  const int NB = (N + TPB - 1) / TPB;
  const int EB = (E + TPB - 1) / TPB;

  // graph preprocessing + weight transpose (once per call; reused by all 3 layers)
  init_k<<<(N * PKS + TPB - 1) / TPB, TPB, 0, stream>>>(pk, N);
  edges_k<<<EB, TPB, 0, stream>>>(ei, ew, pk, pir, E);
  unpack_k<<<NB, TPB, 0, stream>>>(pk, dinv, cnt, N);
  scan_a<<<NB, TPB, 0, stream>>>(cnt, rp, bsum, N);
  scan_b<<<1, 512, 0, stream>>>(bsum, NB);
  scan_c<<<NB, TPB, 0, stream>>>(rp, bsum, N, E);
  fill_k<<<EB, TPB, 0, stream>>>(ei, ew, dinv, rp, pir, epk, E);
  wt_k<<<160, TPB, 0, stream>>>(W1, W2, W3, wt1, wt2, wt3);

  const int aggBlocks  = (N + 3) / 4;        // one 64-lane wave per node
  const int gemmBlocks = (N + 63) / 64;      // 4 waves x 16 rows per block

  // layer 1: h = x @ W1 (bf16 mfma) ; agg + b1 -> abuf fp32
  gemm_mfma<128, false><<<gemmBlocks, 256, 0, stream>>>(x, wt1, hbuf, N);
  agg128<<<aggBlocks, 256, 0, stream>>>(hbuf, rp, epk, dinv, b1, abuf, N);

  // layer 2: h = relu(a1) @ W2 ; agg + b2 -> abuf fp32
  gemm_mfma<128, true><<<gemmBlocks, 256, 0, stream>>>(abuf, wt2, hbuf, N);
  agg128<<<aggBlocks, 256, 0, stream>>>(hbuf, rp, epk, dinv, b2, abuf, N);

  // layer 3: h = relu(a2) @ W3 ; agg + b3 -> d_out fp32
  gemm_mfma<64, true><<<gemmBlocks, 256, 0, stream>>>(abuf, wt3, hbuf, N);
  agg64<<<aggBlocks, 256, 0, stream>>>(hbuf, rp, epk, dinv, b3, (float*)d_out, N);
}

// Round 14
// 375.459 us; speedup vs baseline: 6.3065x; 1.0256x over previous
//
#include <hip/hip_runtime.h>
#include <cstdint>
#include <cstddef>

#define TPB 256
#define PKS 16   // pk stride in u32 (layout proven perf-neutral in R9; kept)

// fp32 -> bf16 (round to nearest even), as raw ushort
__device__ __forceinline__ unsigned short f2bf(float f) {
  unsigned u = __float_as_uint(f);
  u += 0x7fffu + ((u >> 16) & 1u);
  return (unsigned short)(u >> 16);
}
__device__ __forceinline__ float bf_lo(unsigned u) { return __uint_as_float(u << 16); }
__device__ __forceinline__ float bf_hi(unsigned u) { return __uint_as_float(u & 0xffff0000u); }

#define FIXP32 8192.0f        // 2^13 fixed-point for weighted degree (20-bit field)
#define DEGMASK 0xFFFFFu      // low 20 bits

typedef __attribute__((ext_vector_type(8))) short  short8v;   // 8 bf16 (4 VGPRs)
typedef __attribute__((ext_vector_type(4))) float  float4v;   // MFMA acc

// ---------------- preprocessing ----------------

__global__ void init_k(unsigned* __restrict__ pk, int n) {
  int i = blockIdx.x * TPB + threadIdx.x;
  if (i < n * PKS) pk[i] = 0u;
}

// ONE packed 32-bit atomic per edge: count in high 12 bits, fixed-point weighted
// degree in low 20 bits. Returned old count field = edge's slot within its CSR row.
// (R13 used a 64-bit packed atomic: 72us, throughput-bound at the coherence point.
//  This tests whether that throughput is per-op or per-byte.)
__global__ void edges_k(const int* __restrict__ ei, const float* __restrict__ w,
                        unsigned* __restrict__ pk, int* __restrict__ pir, int E) {
  int e = blockIdx.x * TPB + threadIdx.x;
  if (e >= E) return;
  int d = ei[E + e];
  unsigned v = (1u << 20) | (unsigned)(w[e] * FIXP32 + 0.5f);
  unsigned old = atomicAdd(&pk[(size_t)d * PKS], v);
  pir[e] = (int)(old >> 20);
}

__global__ void unpack_k(const unsigned* __restrict__ pk,
                         float* __restrict__ dinv, int* __restrict__ cnt, int n) {
  int i = blockIdx.x * TPB + threadIdx.x;
  if (i >= n) return;
  unsigned p = pk[(size_t)i * PKS];
  float deg = 1.0f + (float)(p & DEGMASK) * (1.0f / FIXP32);  // self-loop => deg >= 1
  dinv[i] = rsqrtf(deg);
  cnt[i]  = (int)(p >> 20);
}

__global__ void scan_a(const int* __restrict__ cnt, int* __restrict__ rp,
                       int* __restrict__ bsum, int n) {
  __shared__ int s[TPB];
  int i = blockIdx.x * TPB + threadIdx.x;
  int v = (i < n) ? cnt[i] : 0;
  s[threadIdx.x] = v;
  __syncthreads();
  #pragma unroll
  for (int off = 1; off < TPB; off <<= 1) {
    int t = (threadIdx.x >= off) ? s[threadIdx.x - off] : 0;
    __syncthreads();
    s[threadIdx.x] += t;
    __syncthreads();
  }
  if (i < n) rp[i] = s[threadIdx.x] - v;            // exclusive within block
  if (threadIdx.x == TPB - 1) bsum[blockIdx.x] = s[TPB - 1];
}

__global__ void scan_b(int* __restrict__ bsum, int nb) {
  __shared__ int s[512];
  int v = (threadIdx.x < nb) ? bsum[threadIdx.x] : 0;
  s[threadIdx.x] = v;
  __syncthreads();
  #pragma unroll
  for (int off = 1; off < 512; off <<= 1) {
    int t = (threadIdx.x >= off) ? s[threadIdx.x - off] : 0;
    __syncthreads();
    s[threadIdx.x] += t;
    __syncthreads();
  }
  if (threadIdx.x < nb) bsum[threadIdx.x] = s[threadIdx.x] - v;  // exclusive block offsets
}

__global__ void scan_c(int* __restrict__ rp, const int* __restrict__ bsum, int n, int etot) {
  int i = blockIdx.x * TPB + threadIdx.x;
  if (i < n) rp[i] += bsum[blockIdx.x];
  if (blockIdx.x == 0 && threadIdx.x == 0) rp[n] = etot;
}

// no atomic: slot comes from pir[] captured by the packed atomic
__global__ void fill_k(const int* __restrict__ ei, const float* __restrict__ w,
                       const float* __restrict__ dinv, const int* __restrict__ rp,
                       const int* __restrict__ pir, int2* __restrict__ epk, int E) {
  int e = blockIdx.x * TPB + threadIdx.x;
  if (e >= E) return;
  int s = ei[e];
  int d = ei[E + e];
  int pos = rp[d] + pir[e];
  float nrm = dinv[s] * w[e] * dinv[d];
  epk[pos] = make_int2(s, __float_as_int(nrm));
}

// transpose + bf16-convert all three weight matrices: wtX[c][k] = W[k][c]
__global__ void wt_k(const float* __restrict__ W1, const float* __restrict__ W2,
                     const float* __restrict__ W3,
                     unsigned short* __restrict__ wt1, unsigned short* __restrict__ wt2,
                     unsigned short* __restrict__ wt3) {
  int t = blockIdx.x * TPB + threadIdx.x;
  if (t < 16384) {                  // W1 128x128
    int c = t >> 7, k = t & 127;
    wt1[t] = f2bf(W1[k * 128 + c]);
  } else if (t < 32768) {           // W2 128x128
    int u = t - 16384;
    int c = u >> 7, k = u & 127;
    wt2[u] = f2bf(W2[k * 128 + c]);
  } else if (t < 40960) {           // W3 128x64
    int u = t - 32768;
    int c = u >> 7, k = u & 127;
    wt3[u] = f2bf(W3[k * 64 + c]);
  }
}

// ---------------- GEMM via MFMA: H = bf16(act(X)) @ bf16(W), fp32 acc, bf16 out ----

template<int COUT, bool RELU>
__global__ __launch_bounds__(256) void gemm_mfma(const float* __restrict__ X,
                                                 const unsigned short* __restrict__ Wt,
                                                 unsigned short* __restrict__ H, int n) {
  const int lane = threadIdx.x & 63;
  const int wv   = threadIdx.x >> 6;             // 0..3
  const int r0   = (blockIdx.x * 4 + wv) * 16;   // wave's row strip
  if (r0 >= n) return;
  const int c16   = lane & 15;
  const int kb    = (lane >> 4) * 8;             // 0,8,16,24
  const int row_c = min(r0 + c16, n - 1);        // clamp OOB loads

  short8v a[4];
  const float* xrow = X + (size_t)row_c * 128;
  #pragma unroll
  for (int kk = 0; kk < 4; kk++) {
    float4 lo = *(const float4*)(xrow + kk * 32 + kb);
    float4 hi = *(const float4*)(xrow + kk * 32 + kb + 4);
    float v0 = lo.x, v1 = lo.y, v2 = lo.z, v3 = lo.w;
    float v4 = hi.x, v5 = hi.y, v6 = hi.z, v7 = hi.w;
    if (RELU) {
      v0 = fmaxf(v0, 0.f); v1 = fmaxf(v1, 0.f); v2 = fmaxf(v2, 0.f); v3 = fmaxf(v3, 0.f);
      v4 = fmaxf(v4, 0.f); v5 = fmaxf(v5, 0.f); v6 = fmaxf(v6, 0.f); v7 = fmaxf(v7, 0.f);
    }
    short8v t;
    t[0] = (short)f2bf(v0); t[1] = (short)f2bf(v1);
    t[2] = (short)f2bf(v2); t[3] = (short)f2bf(v3);
    t[4] = (short)f2bf(v4); t[5] = (short)f2bf(v5);
    t[6] = (short)f2bf(v6); t[7] = (short)f2bf(v7);
    a[kk] = t;
  }

  constexpr int CT = COUT / 16;
  const int orow = r0 + (lane >> 4) * 4;
  #pragma unroll
  for (int ct = 0; ct < CT; ct++) {
    float4v acc = {0.f, 0.f, 0.f, 0.f};
    const unsigned short* wrow = Wt + (size_t)(ct * 16 + c16) * 128 + kb;
    #pragma unroll
    for (int kk = 0; kk < 4; kk++) {
      short8v b = *(const short8v*)(wrow + kk * 32);
      acc = __builtin_amdgcn_mfma_f32_16x16x32_bf16(a[kk], b, acc, 0, 0, 0);
    }
    const int ocol = ct * 16 + c16;
    #pragma unroll
    for (int r = 0; r < 4; r++) {
      if (orow + r < n)
        H[(size_t)(orow + r) * COUT + ocol] = f2bf(acc[r]);
    }
  }
}

// ---------------- aggregation: one wave per node, CSR gather (bf16 table) ----------
// out[j][c] = b[c] + dinv[j]^2 * h[j][c] + sum_e norm_e * h[col_e][c]
// 16-deep gather unroll: 16 outstanding 256B row-gathers per wave (MLP).

__global__ __launch_bounds__(256) void agg128(const unsigned short* __restrict__ H,
                                              const int* __restrict__ rp,
                                              const int2* __restrict__ epk,
                                              const float* __restrict__ dinv,
                                              const float* __restrict__ bias,
                                              float* __restrict__ OUT, int n) {
  int wid  = __builtin_amdgcn_readfirstlane(blockIdx.x * 4 + (threadIdx.x >> 6));
  int lane = threadIdx.x & 63;
  if (wid >= n) return;
  float di = dinv[wid];
  float w0 = di * di;
  unsigned hv = ((const unsigned*)(H + (size_t)wid * 128))[lane];
  float2 bv = ((const float2*)bias)[lane];
  float ax = bv.x + w0 * bf_lo(hv);
  float ay = bv.y + w0 * bf_hi(hv);
  int e  = rp[wid];
  int e1 = rp[wid + 1];
  for (; e + 15 < e1; e += 16) {
    int2 p[16];
    #pragma unroll
    for (int u = 0; u < 16; u++) p[u] = epk[e + u];
    unsigned h[16];
    #pragma unroll
    for (int u = 0; u < 16; u++) h[u] = ((const unsigned*)(H + (size_t)p[u].x * 128))[lane];
    #pragma unroll
    for (int u = 0; u < 16; u++) {
      float nw = __int_as_float(p[u].y);
      ax += nw * bf_lo(h[u]);
      ay += nw * bf_hi(h[u]);
    }
  }
  for (; e + 3 < e1; e += 4) {
    int2 p[4];
    #pragma unroll
    for (int u = 0; u < 4; u++) p[u] = epk[e + u];
    unsigned h[4];
    #pragma unroll
    for (int u = 0; u < 4; u++) h[u] = ((const unsigned*)(H + (size_t)p[u].x * 128))[lane];
    #pragma unroll
    for (int u = 0; u < 4; u++) {
      float nw = __int_as_float(p[u].y);
      ax += nw * bf_lo(h[u]);
      ay += nw * bf_hi(h[u]);
    }
  }
  for (; e < e1; e++) {
    int2 p = epk[e];
    unsigned h = ((const unsigned*)(H + (size_t)p.x * 128))[lane];
    float nw = __int_as_float(p.y);
    ax += nw * bf_lo(h); ay += nw * bf_hi(h);
  }
  ((float2*)(OUT + (size_t)wid * 128))[lane] = make_float2(ax, ay);
}

__global__ __launch_bounds__(256) void agg64(const unsigned short* __restrict__ H,
                                             const int* __restrict__ rp,
                                             const int2* __restrict__ epk,
                                             const float* __restrict__ dinv,
                                             const float* __restrict__ bias,
                                             float* __restrict__ OUT, int n) {
  int wid  = __builtin_amdgcn_readfirstlane(blockIdx.x * 4 + (threadIdx.x >> 6));
  int lane = threadIdx.x & 63;
  if (wid >= n) return;
  float di = dinv[wid];
  float w0 = di * di;
  float hv = __uint_as_float(((unsigned)H[(size_t)wid * 64 + lane]) << 16);
  float acc = bias[lane] + w0 * hv;
  int e  = rp[wid];
  int e1 = rp[wid + 1];
  for (; e + 15 < e1; e += 16) {
    int2 p[16];
    #pragma unroll
    for (int u = 0; u < 16; u++) p[u] = epk[e + u];
    float h[16];
    #pragma unroll
    for (int u = 0; u < 16; u++)
      h[u] = __uint_as_float(((unsigned)H[(size_t)p[u].x * 64 + lane]) << 16);
    #pragma unroll
    for (int u = 0; u < 16; u++) acc += __int_as_float(p[u].y) * h[u];
  }
  for (; e + 3 < e1; e += 4) {
    int2 p[4];
    #pragma unroll
    for (int u = 0; u < 4; u++) p[u] = epk[e + u];
    float h[4];
    #pragma unroll
    for (int u = 0; u < 4; u++)
      h[u] = __uint_as_float(((unsigned)H[(size_t)p[u].x * 64 + lane]) << 16);
    #pragma unroll
    for (int u = 0; u < 4; u++) acc += __int_as_float(p[u].y) * h[u];
  }
  for (; e < e1; e++) {
    int2 p = epk[e];
    float h = __uint_as_float(((unsigned)H[(size_t)p.x * 64 + lane]) << 16);
    acc += __int_as_float(p.y) * h;
  }
  OUT[(size_t)wid * 64 + lane] = acc;
}

// ---------------- launch ----------------

extern "C" void kernel_launch(void* const* d_in, const int* in_sizes, int n_in,
                              void* d_out, int out_size, void* d_ws, size_t ws_size,
                              hipStream_t stream) {
  const float* x  = (const float*)d_in[0];
  const int*   ei = (const int*)d_in[1];    // int64 in reference -> int32 on device
  const float* ew = (const float*)d_in[2];
  const float* W1 = (const float*)d_in[3];
  const float* b1 = (const float*)d_in[4];
  const float* W2 = (const float*)d_in[5];
  const float* b2 = (const float*)d_in[6];
  const float* W3 = (const float*)d_in[7];
  const float* b3 = (const float*)d_in[8];

  const int N = in_sizes[0] / 128;
  const int E = in_sizes[2];

  char* p = (char*)d_ws;
  auto carve = [&](size_t bytes) -> void* {
    void* r = (void*)p;
    p += (bytes + 255) & ~(size_t)255;
    return r;
  };
  unsigned* pk  = (unsigned*)carve((size_t)N * 4 * PKS);
  float* dinv   = (float*)carve((size_t)N * 4);
  int*   cnt    = (int*)  carve((size_t)N * 4);
  int*   rp     = (int*)  carve((size_t)(N + 1) * 4);
  int*   bsum   = (int*)  carve(512 * 4);
  int*   pir    = (int*)  carve((size_t)E * 4);
  int2*  epk    = (int2*) carve((size_t)E * 8);
  unsigned short* hbuf = (unsigned short*)carve((size_t)N * 128 * 2);  // bf16 table
  float* abuf   = (float*)carve((size_t)N * 128 * 4);
  unsigned short* wt1 = (unsigned short*)carve(16384 * 2);
  unsigned short* wt2 = (unsigned short*)carve(16384 * 2);
  unsigned short* wt3 = (unsigned short*)carve(8192 * 2);

  const int NB = (N + TPB - 1) / TPB;
  const int EB = (E + TPB - 1) / TPB;

  // graph preprocessing + weight transpose (once per call; reused by all 3 layers)
  init_k<<<(N * PKS + TPB - 1) / TPB, TPB, 0, stream>>>(pk, N);
  edges_k<<<EB, TPB, 0, stream>>>(ei, ew, pk, pir, E);
  unpack_k<<<NB, TPB, 0, stream>>>(pk, dinv, cnt, N);
  scan_a<<<NB, TPB, 0, stream>>>(cnt, rp, bsum, N);
  scan_b<<<1, 512, 0, stream>>>(bsum, NB);
  scan_c<<<NB, TPB, 0, stream>>>(rp, bsum, N, E);
  fill_k<<<EB, TPB, 0, stream>>>(ei, ew, dinv, rp, pir, epk, E);
  wt_k<<<160, TPB, 0, stream>>>(W1, W2, W3, wt1, wt2, wt3);

  const int aggBlocks  = (N + 3) / 4;        // one 64-lane wave per node
  const int gemmBlocks = (N + 63) / 64;      // 4 waves x 16 rows per block

  // layer 1: h = x @ W1 (bf16 mfma) ; agg + b1 -> abuf fp32
  gemm_mfma<128, false><<<gemmBlocks, 256, 0, stream>>>(x, wt1, hbuf, N);
  agg128<<<aggBlocks, 256, 0, stream>>>(hbuf, rp, epk, dinv, b1, abuf, N);

  // layer 2: h = relu(a1) @ W2 ; agg + b2 -> abuf fp32
  gemm_mfma<128, true><<<gemmBlocks, 256, 0, stream>>>(abuf, wt2, hbuf, N);
  agg128<<<aggBlocks, 256, 0, stream>>>(hbuf, rp, epk, dinv, b2, abuf, N);

  // layer 3: h = relu(a2) @ W3 ; agg + b3 -> d_out fp32
  gemm_mfma<64, true><<<gemmBlocks, 256, 0, stream>>>(abuf, wt3, hbuf, N);
  agg64<<<aggBlocks, 256, 0, stream>>>(hbuf, rp, epk, dinv, b3, (float*)d_out, N);
}

// Round 15
// 363.080 us; speedup vs baseline: 6.5215x; 1.0341x over previous
//
#include <hip/hip_runtime.h>
#include <cstdint>
#include <cstddef>

#define TPB 256
#define PKS 16   // pk stride in u32 (layout proven perf-neutral in R9; kept)

// fp32 -> bf16 (round to nearest even), as raw ushort
__device__ __forceinline__ unsigned short f2bf(float f) {
  unsigned u = __float_as_uint(f);
  u += 0x7fffu + ((u >> 16) & 1u);
  return (unsigned short)(u >> 16);
}
__device__ __forceinline__ float bf_lo(unsigned u) { return __uint_as_float(u << 16); }
__device__ __forceinline__ float bf_hi(unsigned u) { return __uint_as_float(u & 0xffff0000u); }

#define FIXP32 8192.0f        // 2^13 fixed-point for weighted degree (20-bit field)
#define DEGMASK 0xFFFFFu      // low 20 bits

typedef __attribute__((ext_vector_type(8))) short  short8v;   // 8 bf16 (4 VGPRs)
typedef __attribute__((ext_vector_type(4))) float  float4v;   // MFMA acc

// ---------------- preprocessing ----------------

__global__ void init_k(unsigned* __restrict__ pk, int n) {
  int i = blockIdx.x * TPB + threadIdx.x;
  if (i < n * PKS) pk[i] = 0u;
}

// ONE packed 32-bit atomic per edge: count in high 12 bits, fixed-point weighted
// degree in low 20 bits. Returned old count field = edge's slot within its CSR row.
// (Atomic throughput is per-op ~23G/s at the coherence point — R9/R14 measured; floor.)
__global__ void edges_k(const int* __restrict__ ei, const float* __restrict__ w,
                        unsigned* __restrict__ pk, int* __restrict__ pir, int E) {
  int e = blockIdx.x * TPB + threadIdx.x;
  if (e >= E) return;
  int d = ei[E + e];
  unsigned v = (1u << 20) | (unsigned)(w[e] * FIXP32 + 0.5f);
  unsigned old = atomicAdd(&pk[(size_t)d * PKS], v);
  pir[e] = (int)(old >> 20);
}

__global__ void unpack_k(const unsigned* __restrict__ pk,
                         float* __restrict__ dinv, int* __restrict__ cnt, int n) {
  int i = blockIdx.x * TPB + threadIdx.x;
  if (i >= n) return;
  unsigned p = pk[(size_t)i * PKS];
  float deg = 1.0f + (float)(p & DEGMASK) * (1.0f / FIXP32);  // self-loop => deg >= 1
  dinv[i] = rsqrtf(deg);
  cnt[i]  = (int)(p >> 20);
}

__global__ void scan_a(const int* __restrict__ cnt, int* __restrict__ rp,
                       int* __restrict__ bsum, int n) {
  __shared__ int s[TPB];
  int i = blockIdx.x * TPB + threadIdx.x;
  int v = (i < n) ? cnt[i] : 0;
  s[threadIdx.x] = v;
  __syncthreads();
  #pragma unroll
  for (int off = 1; off < TPB; off <<= 1) {
    int t = (threadIdx.x >= off) ? s[threadIdx.x - off] : 0;
    __syncthreads();
    s[threadIdx.x] += t;
    __syncthreads();
  }
  if (i < n) rp[i] = s[threadIdx.x] - v;            // exclusive within block
  if (threadIdx.x == TPB - 1) bsum[blockIdx.x] = s[TPB - 1];
}

__global__ void scan_b(int* __restrict__ bsum, int nb) {
  __shared__ int s[512];
  int v = (threadIdx.x < nb) ? bsum[threadIdx.x] : 0;
  s[threadIdx.x] = v;
  __syncthreads();
  #pragma unroll
  for (int off = 1; off < 512; off <<= 1) {
    int t = (threadIdx.x >= off) ? s[threadIdx.x - off] : 0;
    __syncthreads();
    s[threadIdx.x] += t;
    __syncthreads();
  }
  if (threadIdx.x < nb) bsum[threadIdx.x] = s[threadIdx.x] - v;  // exclusive block offsets
}

__global__ void scan_c(int* __restrict__ rp, const int* __restrict__ bsum, int n, int etot) {
  int i = blockIdx.x * TPB + threadIdx.x;
  if (i < n) rp[i] += bsum[blockIdx.x];
  if (blockIdx.x == 0 && threadIdx.x == 0) rp[n] = etot;
}

// no atomic: slot comes from pir[] captured by the packed atomic
__global__ void fill_k(const int* __restrict__ ei, const float* __restrict__ w,
                       const float* __restrict__ dinv, const int* __restrict__ rp,
                       const int* __restrict__ pir, int2* __restrict__ epk, int E) {
  int e = blockIdx.x * TPB + threadIdx.x;
  if (e >= E) return;
  int s = ei[e];
  int d = ei[E + e];
  int pos = rp[d] + pir[e];
  float nrm = dinv[s] * w[e] * dinv[d];
  epk[pos] = make_int2(s, __float_as_int(nrm));
}

// transpose + bf16-convert all three weight matrices: wtX[c][k] = W[k][c]
__global__ void wt_k(const float* __restrict__ W1, const float* __restrict__ W2,
                     const float* __restrict__ W3,
                     unsigned short* __restrict__ wt1, unsigned short* __restrict__ wt2,
                     unsigned short* __restrict__ wt3) {
  int t = blockIdx.x * TPB + threadIdx.x;
  if (t < 16384) {                  // W1 128x128
    int c = t >> 7, k = t & 127;
    wt1[t] = f2bf(W1[k * 128 + c]);
  } else if (t < 32768) {           // W2 128x128
    int u = t - 16384;
    int c = u >> 7, k = u & 127;
    wt2[u] = f2bf(W2[k * 128 + c]);
  } else if (t < 40960) {           // W3 128x64
    int u = t - 32768;
    int c = u >> 7, k = u & 127;
    wt3[u] = f2bf(W3[k * 64 + c]);
  }
}

// ---------------- GEMM via MFMA: H = bf16(act(X)) @ bf16(W), fp32 acc, bf16 out ----
// BF16IN: X is already bf16 (the agg output) — pure 16B loads, sign-bit ReLU,
// no conversion. Otherwise X is fp32 (first layer) and is converted on load.

template<int COUT, bool RELU, bool BF16IN>
__global__ __launch_bounds__(256) void gemm_mfma(const void* __restrict__ Xv,
                                                 const unsigned short* __restrict__ Wt,
                                                 unsigned short* __restrict__ H, int n) {
  const int lane = threadIdx.x & 63;
  const int wv   = threadIdx.x >> 6;             // 0..3
  const int r0   = (blockIdx.x * 4 + wv) * 16;   // wave's row strip
  if (r0 >= n) return;
  const int c16   = lane & 15;
  const int kb    = (lane >> 4) * 8;             // 0,8,16,24
  const int row_c = min(r0 + c16, n - 1);        // clamp OOB loads

  short8v a[4];
  if (BF16IN) {
    const unsigned short* xrow = (const unsigned short*)Xv + (size_t)row_c * 128;
    #pragma unroll
    for (int kk = 0; kk < 4; kk++) {
      short8v t = *(const short8v*)(xrow + kk * 32 + kb);
      if (RELU) {
        #pragma unroll
        for (int j = 0; j < 8; j++) t[j] = (short)(t[j] & 0x8000) ? (short)0 : t[j];
      }
      a[kk] = t;
    }
  } else {
    const float* xrow = (const float*)Xv + (size_t)row_c * 128;
    #pragma unroll
    for (int kk = 0; kk < 4; kk++) {
      float4 lo = *(const float4*)(xrow + kk * 32 + kb);
      float4 hi = *(const float4*)(xrow + kk * 32 + kb + 4);
      float v0 = lo.x, v1 = lo.y, v2 = lo.z, v3 = lo.w;
      float v4 = hi.x, v5 = hi.y, v6 = hi.z, v7 = hi.w;
      if (RELU) {
        v0 = fmaxf(v0, 0.f); v1 = fmaxf(v1, 0.f); v2 = fmaxf(v2, 0.f); v3 = fmaxf(v3, 0.f);
        v4 = fmaxf(v4, 0.f); v5 = fmaxf(v5, 0.f); v6 = fmaxf(v6, 0.f); v7 = fmaxf(v7, 0.f);
      }
      short8v t;
      t[0] = (short)f2bf(v0); t[1] = (short)f2bf(v1);
      t[2] = (short)f2bf(v2); t[3] = (short)f2bf(v3);
      t[4] = (short)f2bf(v4); t[5] = (short)f2bf(v5);
      t[6] = (short)f2bf(v6); t[7] = (short)f2bf(v7);
      a[kk] = t;
    }
  }

  constexpr int CT = COUT / 16;
  const int orow = r0 + (lane >> 4) * 4;
  #pragma unroll
  for (int ct = 0; ct < CT; ct++) {
    float4v acc = {0.f, 0.f, 0.f, 0.f};
    const unsigned short* wrow = Wt + (size_t)(ct * 16 + c16) * 128 + kb;
    #pragma unroll
    for (int kk = 0; kk < 4; kk++) {
      short8v b = *(const short8v*)(wrow + kk * 32);
      acc = __builtin_amdgcn_mfma_f32_16x16x32_bf16(a[kk], b, acc, 0, 0, 0);
    }
    const int ocol = ct * 16 + c16;
    #pragma unroll
    for (int r = 0; r < 4; r++) {
      if (orow + r < n)
        H[(size_t)(orow + r) * COUT + ocol] = f2bf(acc[r]);
    }
  }
}

// ---------------- aggregation: one wave per node, CSR gather (bf16 table) ----------
// out[j][c] = b[c] + dinv[j]^2 * h[j][c] + sum_e norm_e * h[col_e][c]
// agg128 stores bf16 (the consuming GEMM needs bf16 anyway — bit-identical,
// halves abuf traffic). agg64 stores fp32 (final output).

__global__ __launch_bounds__(256) void agg128(const unsigned short* __restrict__ H,
                                              const int* __restrict__ rp,
                                              const int2* __restrict__ epk,
                                              const float* __restrict__ dinv,
                                              const float* __restrict__ bias,
                                              unsigned* __restrict__ OUT, int n) {
  int wid  = __builtin_amdgcn_readfirstlane(blockIdx.x * 4 + (threadIdx.x >> 6));
  int lane = threadIdx.x & 63;
  if (wid >= n) return;
  float di = dinv[wid];
  float w0 = di * di;
  unsigned hv = ((const unsigned*)(H + (size_t)wid * 128))[lane];
  float2 bv = ((const float2*)bias)[lane];
  float ax = bv.x + w0 * bf_lo(hv);
  float ay = bv.y + w0 * bf_hi(hv);
  int e  = rp[wid];
  int e1 = rp[wid + 1];
  for (; e + 15 < e1; e += 16) {
    int2 p[16];
    #pragma unroll
    for (int u = 0; u < 16; u++) p[u] = epk[e + u];
    unsigned h[16];
    #pragma unroll
    for (int u = 0; u < 16; u++) h[u] = ((const unsigned*)(H + (size_t)p[u].x * 128))[lane];
    #pragma unroll
    for (int u = 0; u < 16; u++) {
      float nw = __int_as_float(p[u].y);
      ax += nw * bf_lo(h[u]);
      ay += nw * bf_hi(h[u]);
    }
  }
  for (; e + 3 < e1; e += 4) {
    int2 p[4];
    #pragma unroll
    for (int u = 0; u < 4; u++) p[u] = epk[e + u];
    unsigned h[4];
    #pragma unroll
    for (int u = 0; u < 4; u++) h[u] = ((const unsigned*)(H + (size_t)p[u].x * 128))[lane];
    #pragma unroll
    for (int u = 0; u < 4; u++) {
      float nw = __int_as_float(p[u].y);
      ax += nw * bf_lo(h[u]);
      ay += nw * bf_hi(h[u]);
    }
  }
  for (; e < e1; e++) {
    int2 p = epk[e];
    unsigned h = ((const unsigned*)(H + (size_t)p.x * 128))[lane];
    float nw = __int_as_float(p.y);
    ax += nw * bf_lo(h); ay += nw * bf_hi(h);
  }
  OUT[(size_t)wid * 64 + lane] = (unsigned)f2bf(ax) | ((unsigned)f2bf(ay) << 16);
}

__global__ __launch_bounds__(256) void agg64(const unsigned short* __restrict__ H,
                                             const int* __restrict__ rp,
                                             const int2* __restrict__ epk,
                                             const float* __restrict__ dinv,
                                             const float* __restrict__ bias,
                                             float* __restrict__ OUT, int n) {
  int wid  = __builtin_amdgcn_readfirstlane(blockIdx.x * 4 + (threadIdx.x >> 6));
  int lane = threadIdx.x & 63;
  if (wid >= n) return;
  float di = dinv[wid];
  float w0 = di * di;
  float hv = __uint_as_float(((unsigned)H[(size_t)wid * 64 + lane]) << 16);
  float acc = bias[lane] + w0 * hv;
  int e  = rp[wid];
  int e1 = rp[wid + 1];
  for (; e + 15 < e1; e += 16) {
    int2 p[16];
    #pragma unroll
    for (int u = 0; u < 16; u++) p[u] = epk[e + u];
    float h[16];
    #pragma unroll
    for (int u = 0; u < 16; u++)
      h[u] = __uint_as_float(((unsigned)H[(size_t)p[u].x * 64 + lane]) << 16);
    #pragma unroll
    for (int u = 0; u < 16; u++) acc += __int_as_float(p[u].y) * h[u];
  }
  for (; e + 3 < e1; e += 4) {
    int2 p[4];
    #pragma unroll
    for (int u = 0; u < 4; u++) p[u] = epk[e + u];
    float h[4];
    #pragma unroll
    for (int u = 0; u < 4; u++)
      h[u] = __uint_as_float(((unsigned)H[(size_t)p[u].x * 64 + lane]) << 16);
    #pragma unroll
    for (int u = 0; u < 4; u++) acc += __int_as_float(p[u].y) * h[u];
  }
  for (; e < e1; e++) {
    int2 p = epk[e];
    float h = __uint_as_float(((unsigned)H[(size_t)p.x * 64 + lane]) << 16);
    acc += __int_as_float(p.y) * h;
  }
  OUT[(size_t)wid * 64 + lane] = acc;
}

// ---------------- launch ----------------

extern "C" void kernel_launch(void* const* d_in, const int* in_sizes, int n_in,
                              void* d_out, int out_size, void* d_ws, size_t ws_size,
                              hipStream_t stream) {
  const float* x  = (const float*)d_in[0];
  const int*   ei = (const int*)d_in[1];    // int64 in reference -> int32 on device
  const float* ew = (const float*)d_in[2];
  const float* W1 = (const float*)d_in[3];
  const float* b1 = (const float*)d_in[4];
  const float* W2 = (const float*)d_in[5];
  const float* b2 = (const float*)d_in[6];
  const float* W3 = (const float*)d_in[7];
  const float* b3 = (const float*)d_in[8];

  const int N = in_sizes[0] / 128;
  const int E = in_sizes[2];

  char* p = (char*)d_ws;
  auto carve = [&](size_t bytes) -> void* {
    void* r = (void*)p;
    p += (bytes + 255) & ~(size_t)255;
    return r;
  };
  unsigned* pk  = (unsigned*)carve((size_t)N * 4 * PKS);
  float* dinv   = (float*)carve((size_t)N * 4);
  int*   cnt    = (int*)  carve((size_t)N * 4);
  int*   rp     = (int*)  carve((size_t)(N + 1) * 4);
  int*   bsum   = (int*)  carve(512 * 4);
  int*   pir    = (int*)  carve((size_t)E * 4);
  int2*  epk    = (int2*) carve((size_t)E * 8);
  unsigned short* hbuf = (unsigned short*)carve((size_t)N * 128 * 2);  // bf16 gemm out
  unsigned* abuf = (unsigned*)carve((size_t)N * 128 * 2);              // bf16 agg out
  unsigned short* wt1 = (unsigned short*)carve(16384 * 2);
  unsigned short* wt2 = (unsigned short*)carve(16384 * 2);
  unsigned short* wt3 = (unsigned short*)carve(8192 * 2);

  const int NB = (N + TPB - 1) / TPB;
  const int EB = (E + TPB - 1) / TPB;

  // graph preprocessing + weight transpose (once per call; reused by all 3 layers)
  init_k<<<(N * PKS + TPB - 1) / TPB, TPB, 0, stream>>>(pk, N);
  edges_k<<<EB, TPB, 0, stream>>>(ei, ew, pk, pir, E);
  unpack_k<<<NB, TPB, 0, stream>>>(pk, dinv, cnt, N);
  scan_a<<<NB, TPB, 0, stream>>>(cnt, rp, bsum, N);
  scan_b<<<1, 512, 0, stream>>>(bsum, NB);
  scan_c<<<NB, TPB, 0, stream>>>(rp, bsum, N, E);
  fill_k<<<EB, TPB, 0, stream>>>(ei, ew, dinv, rp, pir, epk, E);
  wt_k<<<160, TPB, 0, stream>>>(W1, W2, W3, wt1, wt2, wt3);

  const int aggBlocks  = (N + 3) / 4;        // one 64-lane wave per node
  const int gemmBlocks = (N + 63) / 64;      // 4 waves x 16 rows per block

  // layer 1: h = x @ W1 (bf16 mfma) ; agg + b1 -> abuf bf16
  gemm_mfma<128, false, false><<<gemmBlocks, 256, 0, stream>>>(x, wt1, hbuf, N);
  agg128<<<aggBlocks, 256, 0, stream>>>(hbuf, rp, epk, dinv, b1, abuf, N);

  // layer 2: h = relu(a1) @ W2 ; agg + b2 -> abuf bf16
  gemm_mfma<128, true, true><<<gemmBlocks, 256, 0, stream>>>(abuf, wt2, hbuf, N);
  agg128<<<aggBlocks, 256, 0, stream>>>(hbuf, rp, epk, dinv, b2, abuf, N);

  // layer 3: h = relu(a2) @ W3 ; agg + b3 -> d_out fp32
  gemm_mfma<64, true, true><<<gemmBlocks, 256, 0, stream>>>(abuf, wt3, hbuf, N);
  agg64<<<aggBlocks, 256, 0, stream>>>(hbuf, rp, epk, dinv, b3, (float*)d_out, N);
}